// Round 4
// baseline (331.462 us; speedup 1.0000x reference)
//
#include <hip/hip_runtime.h>
#include <hip/hip_bf16.h>

// GCN 2-layer: h1 = relu(GCNConv(x, W1, b1)); out = log_softmax(GCNConv(h1, W2, b2))
// GCNConv(h)[d] = dinv[d] * ( sum_{s->d} (h@W)[s]*dinv[s] + (h@W)[d]*dinv[d] ) + b
//
// Round-14: perm is dead (r12 global: +21us, r13 bucket-local: +12.6us —
// indirection breaks coalesced self-term reads + output writes; degree
// divergence is NOT the gather bottleneck). This round attacks preprocessing:
// replace the 4-kernel bucket pipeline (hist/scan/partition/bucket_csr, ~5
// passes over edge data + 2 LDS prefix scans + 361K bank conflicts) with a
// direct global-atomic CSR: k_deg (1.6M atomics over 100K addresses, low
// contention — unlike r11's 64-address disaster), k_scan1, k_fix (row_start/
// cursor/dinv), k_fill (pos=atomicAdd(cursor[dst]); col[pos]=src).
// Gathers unchanged from the 185us baseline (no perm).

#define FEAT_IN 64
#define FEAT_H  32
#define FEAT_O  16
#define MAXSNB  128   // max scan blocks (n <= 131072)

__device__ __forceinline__ float2 upk_bf2(unsigned w) {
    return make_float2(__uint_as_float(w << 16), __uint_as_float(w & 0xFFFF0000u));
}

// ---- degree count: 1.6M atomics spread over 100K addresses ----
__global__ void k_deg(const int4* __restrict__ dst4, int e4, int rem, const int* __restrict__ dst_tail,
                      int* __restrict__ deg) {
    int i = blockIdx.x * blockDim.x + threadIdx.x;
    int stride = gridDim.x * blockDim.x;
    for (int j = i; j < e4; j += stride) {
        int4 d = dst4[j];
        atomicAdd(&deg[d.x], 1);
        atomicAdd(&deg[d.y], 1);
        atomicAdd(&deg[d.z], 1);
        atomicAdd(&deg[d.w], 1);
    }
    if (blockIdx.x == 0 && threadIdx.x < rem) atomicAdd(&deg[dst_tail[threadIdx.x]], 1);
}

// ---- block-local exclusive scan (1024 items/block); bsum[b] = raw block sum ----
__global__ void k_scan1(const int* __restrict__ in, int* __restrict__ out,
                        int* __restrict__ bsum, int len) {
    __shared__ int s[256];
    int t = threadIdx.x;
    int base = blockIdx.x * 1024 + t * 4;
    int a0 = (base + 0) < len ? in[base + 0] : 0;
    int a1 = (base + 1) < len ? in[base + 1] : 0;
    int a2 = (base + 2) < len ? in[base + 2] : 0;
    int a3 = (base + 3) < len ? in[base + 3] : 0;
    int tsum = a0 + a1 + a2 + a3;
    s[t] = tsum;
    __syncthreads();
    for (int off = 1; off < 256; off <<= 1) {
        int x = (t >= off) ? s[t - off] : 0;
        __syncthreads();
        s[t] += x;
        __syncthreads();
    }
    int ex = s[t] - tsum;
    if (base + 0 < len) out[base + 0] = ex;
    if (base + 1 < len) out[base + 1] = ex + a0;
    if (base + 2 < len) out[base + 2] = ex + a0 + a1;
    if (base + 3 < len) out[base + 3] = ex + a0 + a1 + a2;
    if (t == 255) bsum[blockIdx.x] = s[255];
}

// helper: LDS-exclusive-scan of raw bsum[snb] into sps[]
__device__ __forceinline__ void scan_bsum(const int* __restrict__ bsum, int snb,
                                          int* __restrict__ sps, int t) {
    if (t < snb) sps[t] = bsum[t];
    __syncthreads();
    if (t == 0) {
        int acc = 0;
        for (int i = 0; i < snb; ++i) { int v = sps[i]; sps[i] = acc; acc += v; }
    }
    __syncthreads();
}

// ---- finalize: row_start = ebase + block offset; cursor copy; dinv ----
__global__ void k_fix(const int* __restrict__ ebase, const int* __restrict__ bsum, int snb,
                      const int* __restrict__ deg, int n, int e,
                      int* __restrict__ row_start, int* __restrict__ cursor,
                      float* __restrict__ dinv) {
    __shared__ int sps[MAXSNB];
    int t = threadIdx.x;
    scan_bsum(bsum, snb, sps, t);
    int i = blockIdx.x * 256 + t;
    if (i < n) {
        int r = ebase[i] + sps[i >> 10];
        row_start[i] = r;
        cursor[i] = r;
        dinv[i] = rsqrtf((float)deg[i] + 1.0f);  // +1 self-loop
    }
    if (blockIdx.x == 0 && t == 0) row_start[n] = e;
}

// ---- CSR fill: col[atomicAdd(cursor[dst])] = src ----
__global__ void k_fill(const int4* __restrict__ src4, const int4* __restrict__ dst4,
                       int e4, int rem, const int* __restrict__ src_tail,
                       const int* __restrict__ dst_tail,
                       int* __restrict__ cursor, int* __restrict__ col) {
    int i = blockIdx.x * blockDim.x + threadIdx.x;
    int stride = gridDim.x * blockDim.x;
    for (int j = i; j < e4; j += stride) {
        int4 s = src4[j];
        int4 d = dst4[j];
        col[atomicAdd(&cursor[d.x], 1)] = s.x;
        col[atomicAdd(&cursor[d.y], 1)] = s.y;
        col[atomicAdd(&cursor[d.z], 1)] = s.z;
        col[atomicAdd(&cursor[d.w], 1)] = s.w;
    }
    if (blockIdx.x == 0 && threadIdx.x < rem)
        col[atomicAdd(&cursor[dst_tail[threadIdx.x]], 1)] = src_tail[threadIdx.x];
}

// ---- layer 1 GEMM: h1s(bf16) = (x @ W1) * dinv ; 32 nodes/block ----
__global__ void k_gemm1(const float* __restrict__ x, const float* __restrict__ W1,
                        const float* __restrict__ dinv,
                        __hip_bfloat162* __restrict__ h1s2, int n) {
    __shared__ float sW[FEAT_IN * FEAT_H];   // 8 KB
    __shared__ float sx[16][FEAT_IN + 1];
    int t = threadIdx.x;
    for (int i = t; i < FEAT_IN * FEAT_H; i += 256) sW[i] = W1[i];
#pragma unroll
    for (int tile = 0; tile < 2; ++tile) {
        int nodeBase = blockIdx.x * 32 + tile * 16;
        __syncthreads();
        {   // stage 16 nodes of x
            int xn = t >> 4, c = t & 15;
            int node = nodeBase + xn;
            if (node < n) {
                float4 v = ((const float4*)x)[(size_t)node * 16 + c];
                sx[xn][c * 4 + 0] = v.x; sx[xn][c * 4 + 1] = v.y;
                sx[xn][c * 4 + 2] = v.z; sx[xn][c * 4 + 3] = v.w;
            }
        }
        __syncthreads();
        int nl = t >> 4, g = t & 15;
        int node = nodeBase + nl;
        if (node < n) {
            float a0 = 0.0f, a1 = 0.0f;
#pragma unroll
            for (int k = 0; k < FEAT_IN; ++k) {
                float s = sx[nl][k];
                a0 += s * sW[k * FEAT_H + 2 * g];
                a1 += s * sW[k * FEAT_H + 2 * g + 1];
            }
            float dv = dinv[node];
            __hip_bfloat162 o;
            o.x = __float2bfloat16(a0 * dv);
            o.y = __float2bfloat16(a1 * dv);
            h1s2[(size_t)node * 16 + g] = o;
        }
    }
}

// ---- gather layer1 (+relu+bias) fused with GEMM2: 64 nodes x 4 lanes ----
__global__ void k_gather1_gemm2(const int* __restrict__ row_start, const int* __restrict__ col,
                                const uint4* __restrict__ h1q, const float* __restrict__ W2,
                                const float* __restrict__ b1,
                                const float* __restrict__ dinv,
                                __hip_bfloat162* __restrict__ h2s2, int n) {
    __shared__ float sW[FEAT_H * FEAT_O];
    __shared__ float sb1[FEAT_H];
    __shared__ float sz[64][FEAT_H + 1];
    int t = threadIdx.x;
    for (int i = t; i < FEAT_H * FEAT_O; i += 256) sW[i] = W2[i];
    if (t < FEAT_H) sb1[t] = b1[t];
    __syncthreads();

    int g = t >> 2, l = t & 3;          // 64 nodes, 4 lanes each (16B bf16 = 8 feats)
    int d = blockIdx.x * 64 + g;
    if (d < n) {
        float a[8];
        {   // self-loop term
            uint4 u = h1q[(size_t)d * 4 + l];
            float2 p;
            p = upk_bf2(u.x); a[0] = p.x; a[1] = p.y;
            p = upk_bf2(u.y); a[2] = p.x; a[3] = p.y;
            p = upk_bf2(u.z); a[4] = p.x; a[5] = p.y;
            p = upk_bf2(u.w); a[6] = p.x; a[7] = p.y;
        }
        int beg = row_start[d], end = row_start[d + 1];
        int j = beg;
        for (; j + 4 <= end; j += 4) {   // 4 independent 16B gathers in flight
            int c0 = col[j + 0], c1 = col[j + 1], c2 = col[j + 2], c3 = col[j + 3];
            uint4 u0 = h1q[(size_t)c0 * 4 + l];
            uint4 u1 = h1q[(size_t)c1 * 4 + l];
            uint4 u2 = h1q[(size_t)c2 * 4 + l];
            uint4 u3 = h1q[(size_t)c3 * 4 + l];
            float2 p;
            p = upk_bf2(u0.x); a[0] += p.x; a[1] += p.y;
            p = upk_bf2(u0.y); a[2] += p.x; a[3] += p.y;
            p = upk_bf2(u0.z); a[4] += p.x; a[5] += p.y;
            p = upk_bf2(u0.w); a[6] += p.x; a[7] += p.y;
            p = upk_bf2(u1.x); a[0] += p.x; a[1] += p.y;
            p = upk_bf2(u1.y); a[2] += p.x; a[3] += p.y;
            p = upk_bf2(u1.z); a[4] += p.x; a[5] += p.y;
            p = upk_bf2(u1.w); a[6] += p.x; a[7] += p.y;
            p = upk_bf2(u2.x); a[0] += p.x; a[1] += p.y;
            p = upk_bf2(u2.y); a[2] += p.x; a[3] += p.y;
            p = upk_bf2(u2.z); a[4] += p.x; a[5] += p.y;
            p = upk_bf2(u2.w); a[6] += p.x; a[7] += p.y;
            p = upk_bf2(u3.x); a[0] += p.x; a[1] += p.y;
            p = upk_bf2(u3.y); a[2] += p.x; a[3] += p.y;
            p = upk_bf2(u3.z); a[4] += p.x; a[5] += p.y;
            p = upk_bf2(u3.w); a[6] += p.x; a[7] += p.y;
        }
        for (; j < end; ++j) {
            uint4 u = h1q[(size_t)col[j] * 4 + l];
            float2 p;
            p = upk_bf2(u.x); a[0] += p.x; a[1] += p.y;
            p = upk_bf2(u.y); a[2] += p.x; a[3] += p.y;
            p = upk_bf2(u.z); a[4] += p.x; a[5] += p.y;
            p = upk_bf2(u.w); a[6] += p.x; a[7] += p.y;
        }
        float dv = dinv[d];
#pragma unroll
        for (int k = 0; k < 8; ++k)
            sz[g][l * 8 + k] = fmaxf(dv * a[k] + sb1[l * 8 + k], 0.0f);
    }
    __syncthreads();
    // GEMM2: 64 nodes x 8 output-pairs = 512 items / 256 thr = 2 iters; bf16 store
#pragma unroll
    for (int it = 0; it < 2; ++it) {
        int nl = (t >> 3) + it * 32;
        int m = t & 7;
        int node = blockIdx.x * 64 + nl;
        if (node < n) {
            float a0 = 0.0f, a1 = 0.0f;
#pragma unroll
            for (int f = 0; f < FEAT_H; ++f) {
                float z = sz[nl][f];
                a0 += z * sW[f * FEAT_O + 2 * m];
                a1 += z * sW[f * FEAT_O + 2 * m + 1];
            }
            float dv = dinv[node];
            __hip_bfloat162 o;
            o.x = __float2bfloat16(a0 * dv);
            o.y = __float2bfloat16(a1 * dv);
            h2s2[(size_t)node * 8 + m] = o;
        }
    }
}

// ---- gather layer2 + bias + log_softmax: 128 nodes x 2 lanes ----
__global__ void k_gather2_lsm(const int* __restrict__ row_start, const int* __restrict__ col,
                              const uint4* __restrict__ h2q, const float* __restrict__ b2,
                              const float* __restrict__ dinv,
                              float4* __restrict__ out4, int n) {
    __shared__ float sb2[FEAT_O];
    int t = threadIdx.x;
    if (t < FEAT_O) sb2[t] = b2[t];
    __syncthreads();
    int g = t >> 1, h = t & 1;          // 128 nodes, 2 lanes each (16B bf16 = 8 feats)
    int d = blockIdx.x * 128 + g;
    if (d >= n) return;
    float a[8];
    {
        uint4 u = h2q[(size_t)d * 2 + h];  // self-loop term
        float2 p;
        p = upk_bf2(u.x); a[0] = p.x; a[1] = p.y;
        p = upk_bf2(u.y); a[2] = p.x; a[3] = p.y;
        p = upk_bf2(u.z); a[4] = p.x; a[5] = p.y;
        p = upk_bf2(u.w); a[6] = p.x; a[7] = p.y;
    }
    int beg = row_start[d], end = row_start[d + 1];
    int j = beg;
    for (; j + 4 <= end; j += 4) {
        int c0 = col[j + 0], c1 = col[j + 1], c2 = col[j + 2], c3 = col[j + 3];
        uint4 u0 = h2q[(size_t)c0 * 2 + h];
        uint4 u1 = h2q[(size_t)c1 * 2 + h];
        uint4 u2 = h2q[(size_t)c2 * 2 + h];
        uint4 u3 = h2q[(size_t)c3 * 2 + h];
        float2 p;
        p = upk_bf2(u0.x); a[0] += p.x; a[1] += p.y;
        p = upk_bf2(u0.y); a[2] += p.x; a[3] += p.y;
        p = upk_bf2(u0.z); a[4] += p.x; a[5] += p.y;
        p = upk_bf2(u0.w); a[6] += p.x; a[7] += p.y;
        p = upk_bf2(u1.x); a[0] += p.x; a[1] += p.y;
        p = upk_bf2(u1.y); a[2] += p.x; a[3] += p.y;
        p = upk_bf2(u1.z); a[4] += p.x; a[5] += p.y;
        p = upk_bf2(u1.w); a[6] += p.x; a[7] += p.y;
        p = upk_bf2(u2.x); a[0] += p.x; a[1] += p.y;
        p = upk_bf2(u2.y); a[2] += p.x; a[3] += p.y;
        p = upk_bf2(u2.z); a[4] += p.x; a[5] += p.y;
        p = upk_bf2(u2.w); a[6] += p.x; a[7] += p.y;
        p = upk_bf2(u3.x); a[0] += p.x; a[1] += p.y;
        p = upk_bf2(u3.y); a[2] += p.x; a[3] += p.y;
        p = upk_bf2(u3.z); a[4] += p.x; a[5] += p.y;
        p = upk_bf2(u3.w); a[6] += p.x; a[7] += p.y;
    }
    for (; j < end; ++j) {
        uint4 u = h2q[(size_t)col[j] * 2 + h];
        float2 p;
        p = upk_bf2(u.x); a[0] += p.x; a[1] += p.y;
        p = upk_bf2(u.y); a[2] += p.x; a[3] += p.y;
        p = upk_bf2(u.z); a[4] += p.x; a[5] += p.y;
        p = upk_bf2(u.w); a[6] += p.x; a[7] += p.y;
    }
    float dv = dinv[d];
    float v[8];
    float mx = -1e30f;
#pragma unroll
    for (int k = 0; k < 8; ++k) {
        v[k] = dv * a[k] + sb2[h * 8 + k];
        mx = fmaxf(mx, v[k]);
    }
    mx = fmaxf(mx, __shfl_xor(mx, 1));   // partner lane = same node, other half
    float ssum = 0.0f;
#pragma unroll
    for (int k = 0; k < 8; ++k) ssum += __expf(v[k] - mx);
    ssum += __shfl_xor(ssum, 1);
    float lg = mx + logf(ssum);
    float4 o0 = { v[0] - lg, v[1] - lg, v[2] - lg, v[3] - lg };
    float4 o1 = { v[4] - lg, v[5] - lg, v[6] - lg, v[7] - lg };
    out4[(size_t)d * 4 + h * 2 + 0] = o0;
    out4[(size_t)d * 4 + h * 2 + 1] = o1;
}

extern "C" void kernel_launch(void* const* d_in, const int* in_sizes, int n_in,
                              void* d_out, int out_size, void* d_ws, size_t ws_size,
                              hipStream_t stream) {
    const float* x  = (const float*)d_in[0];
    const int*   ei = (const int*)d_in[1];
    const float* W1 = (const float*)d_in[2];
    const float* b1 = (const float*)d_in[3];
    const float* W2 = (const float*)d_in[4];
    const float* b2 = (const float*)d_in[5];

    const int n = in_sizes[0] / FEAT_IN;   // 100000
    const int e = in_sizes[1] / 2;         // 1600000
    const int* src = ei;
    const int* dst = ei + e;
    const int snb = (n + 1023) / 1024;     // 98 (<= MAXSNB)
    const int e4 = e >> 2, rem = e & 3;

    // workspace
    int* col = (int*)d_ws;                                    // e ints (6.4MB)
    __hip_bfloat162* h1s2 = (__hip_bfloat162*)(col + e);      // 16n bf162 (6.4MB)
    __hip_bfloat162* h2s2 = h1s2 + 16 * (size_t)n;            // 8n bf162 (3.2MB)
    float* dinv = (float*)(h2s2 + 8 * (size_t)n);             // n
    int* deg       = (int*)(dinv + n);                        // n
    int* ebase     = deg + n;                                 // n
    int* bsum      = ebase + n;                               // snb
    int* row_start = bsum + MAXSNB;                           // n+1
    int* cursor    = row_start + n + 1;                       // n

    hipMemsetAsync(deg, 0, (size_t)n * sizeof(int), stream);
    k_deg<<<1024, 256, 0, stream>>>((const int4*)dst, e4, rem, dst + e4 * 4, deg);
    k_scan1<<<snb, 256, 0, stream>>>(deg, ebase, bsum, n);
    k_fix<<<(n + 255) / 256, 256, 0, stream>>>(ebase, bsum, snb, deg, n, e,
                                               row_start, cursor, dinv);
    k_fill<<<1024, 256, 0, stream>>>((const int4*)src, (const int4*)dst, e4, rem,
                                     src + e4 * 4, dst + e4 * 4, cursor, col);

    k_gemm1<<<(n + 31) / 32, 256, 0, stream>>>(x, W1, dinv, h1s2, n);
    k_gather1_gemm2<<<(n + 63) / 64, 256, 0, stream>>>(row_start, col, (const uint4*)h1s2,
                                                       W2, b1, dinv, h2s2, n);
    k_gather2_lsm<<<(n + 127) / 128, 256, 0, stream>>>(row_start, col, (const uint4*)h2s2,
                                                       b2, dinv, (float4*)d_out, n);
}